// Round 6
// baseline (581.251 us; speedup 1.0000x reference)
//
#include <hip/hip_runtime.h>
#include <hip/hip_cooperative_groups.h>
#include <stdint.h>
#include <math.h>

namespace cg = cooperative_groups;

#define B_     4
#define HW     36864
#define NPIX   147456
#define NG4    36864           // NPIX/4 pixel-groups
#define GPB    9216            // groups per batch
#define C_ALL  90
#define HBINS  32768           // fine bins: key bits 30..16
#define CAP    1536            // bin-b* list capacity (expected ~150)
#define NSL    128             // gather slices per batch
#define SLPX   288             // pixels per slice (128*288 == HW)
#define NCAND  (NSL*5)         // 640 tail candidates per batch
#define GRID   512
#define NTHR   256
#define TOTTHR (GRID*NTHR)     // 131072
#define SPTOT  (B_*C_ALL*GPB)  // 3,317,760 float4 groups
#define INV    0xFFFFFFFFu

// ---- workspace layout (bytes), all 16B-aligned ----
#define OFF_HIST  0u           // 4*HBINS*4 = 524288
#define OFF_KEY   524288u      // NPIX*4    = 589824
#define OFF_G     1114112u     // NPIX      = 147456
#define OFF_SELX  1261568u     // NPIX      = 147456
#define OFF_SELC  1409024u     // NG4*4     = 147456
#define OFF_RES   1556480u     // 48: b2[4], usage[4], hl[4]
#define OFF_GCNT  1556528u     // 16
#define OFF_GLIST 1556544u     // 4*CAP*8 = 49152
#define OFF_CAND  1605696u     // 4*NCAND*8 = 20480

__device__ __forceinline__ uint32_t costOf(uint32_t g) {
    return g == 0u ? 10u : (g == 1u ? 5u : 2u);
}

// budget_per_sample = float32(budget / B); usage,c exact ints ->
// usage+c <= bps  <=>  usage+c <= floor(bps)
__device__ __forceinline__ uint32_t budgetInt(const int* bptr) {
    double bps = (double)bptr[0] / (double)B_;
    float f = (float)bps;
    return (uint32_t)floorf(f);
}

// compare-exchange keeping max in x (descending)
#define CE(x, y) { uint64_t _mn = (x) < (y) ? (x) : (y); \
                   uint64_t _mx = (x) < (y) ? (y) : (x); (x) = _mx; (y) = _mn; }

union SMem {
    uint32_t csum[256];                                     // cut
    struct { uint64_t red5[4]; uint64_t red2[4][4]; } gat;  // gather
    struct { uint64_t e[CAP]; uint64_t s[CAP]; uint64_t cd[NCAND]; } fin; // 29696 B
};

__global__ __launch_bounds__(NTHR, 2) void k_all(
        const float* __restrict__ collab, const float* __restrict__ util,
        const int* __restrict__ budget_ptr, uint8_t* __restrict__ ws,
        float* __restrict__ outSparse, float* __restrict__ outSel)
{
    cg::grid_group gr = cg::this_grid();
    uint32_t* hist  = (uint32_t*)(ws + OFF_HIST);
    uint32_t* key   = (uint32_t*)(ws + OFF_KEY);
    uint8_t*  gArr  = ws + OFF_G;
    uint8_t*  selx  = ws + OFF_SELX;
    uint32_t* selc  = (uint32_t*)(ws + OFF_SELC);
    uint32_t* res   = (uint32_t*)(ws + OFF_RES);
    uint32_t* gcnt  = (uint32_t*)(ws + OFF_GCNT);
    uint64_t* glist = (uint64_t*)(ws + OFF_GLIST);
    uint64_t* cand  = (uint64_t*)(ws + OFF_CAND);

    const int t = threadIdx.x;
    const int bid = blockIdx.x;
    const uint32_t gtid = (uint32_t)bid * NTHR + (uint32_t)t;
    const int lane = t & 63, wv = t >> 6;
    const uint32_t budget = budgetInt(budget_ptr);

    __shared__ SMem sm;

    // ================= Phase 0: zero hist + gcnt =================
    if (gtid < HBINS) ((uint4*)hist)[gtid] = make_uint4(0u, 0u, 0u, 0u);
    if (gtid == HBINS) { gcnt[0] = 0u; gcnt[1] = 0u; gcnt[2] = 0u; gcnt[3] = 0u; }
    __threadfence();
    gr.sync();

    // ================= Phase 1: prep (key/g/selx + fine hist) =================
    if (gtid < NG4) {
        const float4* u4 = (const float4*)util + (size_t)gtid * 3;
        float4 ua = u4[0], ub = u4[1], uc = u4[2];
        float u[4][3] = { {ua.x, ua.y, ua.z}, {ua.w, ub.x, ub.y},
                          {ub.z, ub.w, uc.x}, {uc.y, uc.z, uc.w} };
        uint32_t kk[4]; uint32_t gpack = 0;
        #pragma unroll
        for (int p = 0; p < 4; ++p) {
            float best = u[p][0]; uint32_t gq = 0;
            if (u[p][1] > best) { best = u[p][1]; gq = 1; }   // strict > = first max
            if (u[p][2] > best) { best = u[p][2]; gq = 2; }
            kk[p] = (best > 0.0f) ? (__float_as_uint(best) | 0x80000000u) : 0u;
            gpack |= gq << (8 * p);
        }
        ((uint4*)key)[gtid] = make_uint4(kk[0], kk[1], kk[2], kk[3]);
        ((uint32_t*)gArr)[gtid] = gpack;
        ((uint32_t*)selx)[gtid] = 0u;
        uint32_t b = gtid / GPB;
        #pragma unroll
        for (int p = 0; p < 4; ++p)
            if (kk[p])
                atomicAdd(&hist[(size_t)b * HBINS + ((kk[p] >> 16) & 32767u)],
                          costOf((gpack >> (8 * p)) & 3u));
    }
    __threadfence();
    gr.sync();

    // ================= Phase 2: cut (blocks 0..3, batch = bid) =================
    if (bid < B_) {
        const uint32_t* hb = hist + (size_t)bid * HBINS;
        const uint4* h4 = (const uint4*)(hb + (size_t)t * 128);
        uint32_t ssum = 0;
        #pragma unroll 8
        for (int j = 0; j < 32; ++j) { uint4 vv = h4[j]; ssum += vv.x + vv.y + vv.z + vv.w; }
        sm.csum[t] = ssum;
        __syncthreads();
        if (wv == 0) {
            // coarse descending cumsum, 4 chunks(128 bins)/lane
            int hi = 255 - 4 * lane;
            uint32_t c0 = sm.csum[hi], c1 = sm.csum[hi - 1],
                     c2 = sm.csum[hi - 2], c3 = sm.csum[hi - 3];
            uint32_t cs = c0 + c1 + c2 + c3;
            uint32_t v = cs;
            #pragma unroll
            for (int off = 1; off < 64; off <<= 1) {
                uint32_t o = __shfl_up(v, off);
                if (lane >= off) v += o;
            }
            uint32_t excl = v - cs;
            bool found = (excl <= budget) && (v > budget);
            uint32_t cbin = 0, cusage = 0;
            if (found) {
                uint32_t cum = excl;
                if      (cum + c0 > budget) { cbin = (uint32_t)hi;       cusage = cum; }
                else if ((cum += c0) + c1 > budget) { cbin = (uint32_t)(hi - 1); cusage = cum; }
                else if ((cum += c1) + c2 > budget) { cbin = (uint32_t)(hi - 2); cusage = cum; }
                else                        { cbin = (uint32_t)(hi - 3); cusage = cum + c2; }
            }
            unsigned long long msk = __ballot(found);
            if (msk == 0ull) {                     // no crossing: all valid selected
                if (lane == 0) { res[bid] = INV; res[4 + bid] = 0u; res[8 + bid] = 1u; }
            } else {
                int src = __ffsll((long long)msk) - 1;
                cbin   = __shfl(cbin, src);
                cusage = __shfl(cusage, src);
                // fine scan of cbin's 128 bins, 2/lane descending
                const uint32_t* fb = hb + (size_t)cbin * 128;
                int fhi = 127 - 2 * lane;
                uint32_t f0 = fb[fhi], f1 = fb[fhi - 1];
                uint32_t fs = f0 + f1;
                v = fs;
                #pragma unroll
                for (int off = 1; off < 64; off <<= 1) {
                    uint32_t o = __shfl_up(v, off);
                    if (lane >= off) v += o;
                }
                excl = cusage + v - fs;
                found = (excl <= budget) && (excl + fs > budget);
                uint32_t b2 = 0, fusage = 0;
                if (found) {
                    if (excl + f0 > budget) { b2 = cbin * 128u + (uint32_t)fhi;       fusage = excl; }
                    else                    { b2 = cbin * 128u + (uint32_t)(fhi - 1); fusage = excl + f0; }
                }
                msk = __ballot(found);
                src = __ffsll((long long)msk) - 1;  // nonzero by construction
                b2     = __shfl(b2, src);
                fusage = __shfl(fusage, src);
                if (lane == 0) {
                    res[bid]     = b2;
                    res[4 + bid] = fusage;
                    uint32_t bs = b2 + 32768u;
                    res[8 + bid] = (bs >= 65535u) ? INV : ((bs + 1u) << 16);
                }
            }
        }
    }
    __threadfence();
    gr.sync();

    // ================= Phase 3: gather (all 512 blocks) =================
    {
        int gb = bid & 3;                         // batch
        int sl = bid >> 2;                        // slice [0,128)
        uint32_t b2 = res[gb];
        if (b2 != INV) {
            const uint32_t* kb = key + (size_t)gb * HW;
            const uint8_t*  gbp = gArr + (size_t)gb * HW;
            uint64_t m5 = 0, a0 = 0, a1 = 0, a2 = 0, a3 = 0;
            for (int p = t; p < SLPX; p += NTHR) {
                uint32_t pix = (uint32_t)(sl * SLPX + p);
                uint32_t k = kb[pix];
                if (!k) continue;
                uint32_t bin = (k >> 16) & 32767u;
                if (bin == b2) {
                    uint32_t gg = gbp[pix];
                    uint32_t idx = atomicAdd(&gcnt[gb], 1u);
                    if (idx < CAP)   // asc key: (~k, pix) -> utility desc, pix asc
                        glist[(size_t)gb * CAP + idx] =
                            ((uint64_t)(~k) << 32) | ((uint64_t)pix << 2) | (uint64_t)gg;
                } else if (bin < b2) {
                    uint32_t gg = gbp[pix];
                    if (gg) {        // cost-10 never fits (r <= 9 after bin walk)
                        uint64_t m = ((uint64_t)k << 18) | ((uint64_t)(65535u - pix) << 2)
                                   | (uint64_t)gg;
                        if (gg == 1u) { if (m > m5) m5 = m; }
                        else if (m > a3) {
                            if      (m > a0) { a3 = a2; a2 = a1; a1 = a0; a0 = m; }
                            else if (m > a1) { a3 = a2; a2 = a1; a1 = m; }
                            else if (m > a2) { a3 = a2; a2 = m; }
                            else             { a3 = m; }
                        }
                    }
                }
            }
            // wave reduce: max m5; bitonic top-4 merge a0..a3
            #pragma unroll
            for (int off = 32; off; off >>= 1) {
                uint64_t o5 = __shfl_down(m5, off);
                if (o5 > m5) m5 = o5;
                uint64_t b0 = __shfl_down(a0, off), b1 = __shfl_down(a1, off),
                         b2_ = __shfl_down(a2, off), b3 = __shfl_down(a3, off);
                CE(a0, b3); CE(a1, b2_); CE(a2, b1); CE(a3, b0);
                CE(a0, a2); CE(a1, a3); CE(a0, a1); CE(a2, a3);
            }
            if (lane == 0) {
                sm.gat.red5[wv] = m5;
                sm.gat.red2[wv][0] = a0; sm.gat.red2[wv][1] = a1;
                sm.gat.red2[wv][2] = a2; sm.gat.red2[wv][3] = a3;
            }
            __syncthreads();
            if (t == 0) {
                uint64_t g5 = 0, t0 = 0, t1 = 0, t2 = 0, t3 = 0;
                for (int wq = 0; wq < 4; ++wq) {
                    if (sm.gat.red5[wq] > g5) g5 = sm.gat.red5[wq];
                    #pragma unroll
                    for (int q = 0; q < 4; ++q) {
                        uint64_t m = sm.gat.red2[wq][q];
                        if (m > t3) {
                            if      (m > t0) { t3 = t2; t2 = t1; t1 = t0; t0 = m; }
                            else if (m > t1) { t3 = t2; t2 = t1; t1 = m; }
                            else if (m > t2) { t3 = t2; t2 = m; }
                            else             { t3 = m; }
                        }
                    }
                }
                uint64_t* cb_ = cand + ((size_t)gb * NSL + (size_t)sl) * 5;
                cb_[0] = g5; cb_[1] = t0; cb_[2] = t1; cb_[3] = t2; cb_[4] = t3;
            }
        }
    }
    __threadfence();
    gr.sync();

    // ================= Phase 4: final (blocks 0..3) =================
    if (bid < B_) {
        uint32_t b2 = res[bid];
        if (b2 != INV) {
            uint32_t cnt = gcnt[bid];
            int n = (int)(cnt < (uint32_t)CAP ? cnt : (uint32_t)CAP);
            for (int i = t; i < n; i += NTHR) sm.fin.e[i] = glist[(size_t)bid * CAP + i];
            for (int i = t; i < NCAND; i += NTHR) sm.fin.cd[i] = cand[(size_t)bid * NCAND + i];
            __syncthreads();
            for (int i = t; i < n; i += NTHR) {   // rank sort (keys distinct)
                uint64_t ei = sm.fin.e[i];
                int rk = 0;
                for (int j = 0; j < n; ++j) rk += (sm.fin.e[j] < ei);
                sm.fin.s[rk] = ei;
            }
            __syncthreads();
            if (wv == 0) {
                // wave-parallel tail-candidate merge (10 cd entries/lane)
                uint64_t m5 = 0, a0 = 0, a1 = 0, a2 = 0, a3 = 0;
                for (int i = lane; i < NCAND; i += 64) {
                    uint64_t m = sm.fin.cd[i];
                    if (!m) continue;
                    if ((m & 3u) == 1u) { if (m > m5) m5 = m; }
                    else if (m > a3) {
                        if      (m > a0) { a3 = a2; a2 = a1; a1 = a0; a0 = m; }
                        else if (m > a1) { a3 = a2; a2 = a1; a1 = m; }
                        else if (m > a2) { a3 = a2; a2 = m; }
                        else             { a3 = m; }
                    }
                }
                #pragma unroll
                for (int off = 32; off; off >>= 1) {
                    uint64_t o5 = __shfl_down(m5, off);
                    if (o5 > m5) m5 = o5;
                    uint64_t b0 = __shfl_down(a0, off), b1 = __shfl_down(a1, off),
                             b2_ = __shfl_down(a2, off), b3 = __shfl_down(a3, off);
                    CE(a0, b3); CE(a1, b2_); CE(a2, b1); CE(a3, b0);
                    CE(a0, a2); CE(a1, a3); CE(a0, a1); CE(a2, a3);
                }
                if (lane == 0) {
                    // serial greedy within bin b*
                    uint32_t usage = res[4 + bid];
                    uint8_t* sx = selx + (size_t)bid * HW;
                    for (int i = 0; i < n; ++i) {
                        uint64_t ei = sm.fin.s[i];
                        uint32_t c = costOf((uint32_t)(ei & 3u));
                        if (usage + c <= budget) { usage += c; sx[(ei >> 2) & 0xFFFFu] = 1; }
                    }
                    // exact <=5-pick tail replay below bin b*
                    uint64_t c5[5] = { m5, a0, a1, a2, a3 };
                    for (int i = 1; i < 5; ++i) {
                        uint64_t x = c5[i]; int j = i;
                        while (j > 0 && c5[j - 1] < x) { c5[j] = c5[j - 1]; --j; }
                        c5[j] = x;
                    }
                    uint32_t r = budget - usage;   // provably <= 9
                    for (int i = 0; i < 5; ++i) {
                        uint64_t m = c5[i];
                        if (!m) break;
                        uint32_t c = costOf((uint32_t)(m & 3u));
                        if (c <= r) {
                            r -= c;
                            uint32_t pix = 65535u - (uint32_t)((m >> 2) & 0xFFFFu);
                            sx[pix] = 1;
                        }
                    }
                }
            }
        }
    }
    __threadfence();
    gr.sync();

    // ================= Phase 5a: selc byte-map + sel_idx output =================
    if (gtid < NG4) {
        uint32_t b = gtid / GPB;
        uint32_t hl = res[8 + b];                  // >= 1 always
        uint4 kk = ((const uint4*)key)[gtid];
        uint32_t gg = ((const uint32_t*)gArr)[gtid];
        uint32_t sx = ((const uint32_t*)selx)[gtid];
        uint32_t kv[4] = { kk.x, kk.y, kk.z, kk.w };
        uint32_t sel = 0;
        float sf[4];
        #pragma unroll
        for (int p = 0; p < 4; ++p) {
            bool se = (kv[p] >= hl) || (((sx >> (8 * p)) & 0xFFu) != 0u);
            uint32_t gp = (gg >> (8 * p)) & 3u;
            sel |= (se ? gp : 0xFFu) << (8 * p);
            sf[p] = se ? (float)gp : -1.0f;
        }
        selc[gtid] = sel;
        ((float4*)outSel)[gtid] = make_float4(sf[0], sf[1], sf[2], sf[3]);
    }
    __threadfence();
    gr.sync();

    // ================= Phase 5b: masked sparse BEV (grid-stride) =================
    for (uint32_t m = gtid; m < SPTOT; m += TOTTHR) {
        uint32_t p4 = m % GPB;
        uint32_t cb = m / GPB;                     // b*90 + c
        uint32_t c  = cb % C_ALL;
        uint32_t b  = cb / C_ALL;
        uint32_t cls = (c < 10u) ? 0u : ((c < 74u) ? 1u : 2u);
        uint32_t sel = selc[(size_t)b * GPB + p4];
        float4 v = ((const float4*)collab)[(size_t)cb * GPB + p4];
        float4 o;
        o.x = (((sel      ) & 0xFFu) == cls) ? v.x : 0.0f;
        o.y = (((sel >>  8) & 0xFFu) == cls) ? v.y : 0.0f;
        o.z = (((sel >> 16) & 0xFFu) == cls) ? v.z : 0.0f;
        o.w = (((sel >> 24) & 0xFFu) == cls) ? v.w : 0.0f;
        ((float4*)outSparse)[(size_t)cb * GPB + p4] = o;
    }
}

extern "C" void kernel_launch(void* const* d_in, const int* in_sizes, int n_in,
                              void* d_out, int out_size, void* d_ws, size_t ws_size,
                              hipStream_t stream) {
    (void)in_sizes; (void)n_in; (void)out_size; (void)ws_size;
    const float* collab = (const float*)d_in[0];
    const float* util   = (const float*)d_in[1];
    const int*   budget = (const int*)d_in[2];
    uint8_t* ws = (uint8_t*)d_ws;
    float* outSparse = (float*)d_out;
    float* outSel    = outSparse + (size_t)B_ * C_ALL * HW;

    void* args[] = { (void*)&collab, (void*)&util, (void*)&budget,
                     (void*)&ws, (void*)&outSparse, (void*)&outSel };
    hipLaunchCooperativeKernel((const void*)k_all, dim3(GRID), dim3(NTHR),
                               args, 0, stream);
}

// Round 7
// 90.396 us; speedup vs baseline: 6.4300x; 6.4300x over previous
//
#include <hip/hip_runtime.h>
#include <stdint.h>
#include <math.h>

#define B_    4
#define HW    36864
#define NPIX  147456
#define C_V   10
#define C_F   64
#define C_D   16
#define C_ALL 90
#define HBINS 32768              // fine bins: key bits 30..16
#define CAP   1536               // bin-b* list capacity (expected ~50-150)
#define NSL   36                 // gather slices per batch
#define SLPX  1024               // pixels per slice (36*1024 == HW)
#define NCAND (NSL*5)            // 180 tail candidates per batch
#define INV   0xFFFFFFFFu

// ---- workspace layout (bytes), 16B-aligned ----
#define OFF_HIST  0u             // 4*HBINS*4 = 524288 (zeroed)
#define OFF_GCNT  524288u        // 16 (zeroed)
#define OFF_DONE  524304u        // 16 (zeroed)
#define ZERO_U4   32770u         // (524320)/16
#define OFF_KEY   524320u        // NPIX*4 = 589824
#define OFF_G     1114144u       // NPIX
#define OFF_SELX  1261600u       // NPIX (zeroed by k_prep)
#define OFF_RES   1409056u       // 48: b2[4], usage[4], hl[4]
#define OFF_GLIST 1409104u       // 4*CAP*8 = 49152
#define OFF_CAND  1458256u       // 4*NCAND*8 = 5760

__device__ __forceinline__ uint32_t costOf(uint32_t g) {
    return g == 0u ? 10u : (g == 1u ? 5u : 2u);
}

// budget_per_sample = float32(budget / B); usage,c exact ints ->
// usage+c <= bps  <=>  usage+c <= floor(bps)
__device__ __forceinline__ uint32_t budgetInt(const int* bptr) {
    double bps = (double)bptr[0] / (double)B_;
    float f = (float)bps;
    return (uint32_t)floorf(f);
}

// compare-exchange keeping max in x (descending)
#define CE(x, y) { uint64_t _mn = (x) < (y) ? (x) : (y); \
                   uint64_t _mx = (x) < (y) ? (y) : (x); (x) = _mx; (y) = _mn; }

// K0: zero hist + gcnt + done
__global__ void k_zero(uint4* __restrict__ w4) {
    uint32_t i = blockIdx.x * blockDim.x + threadIdx.x;
    if (i < ZERO_U4) w4[i] = make_uint4(0u, 0u, 0u, 0u);
}

// K1: per-pixel best utility / group / sortable key, zero selx, fine hist.
__global__ void k_prep(const float* __restrict__ util, uint4* __restrict__ key4,
                       uint32_t* __restrict__ g4, uint32_t* __restrict__ selx4,
                       uint32_t* __restrict__ hist) {
    int t = blockIdx.x * blockDim.x + threadIdx.x;   // [0, NPIX/4)
    if (t >= NPIX / 4) return;
    const float4* u4 = (const float4*)util + (size_t)t * 3;
    float4 a = u4[0], b4 = u4[1], c4 = u4[2];
    float u[4][3] = { {a.x, a.y, a.z}, {a.w, b4.x, b4.y},
                      {b4.z, b4.w, c4.x}, {c4.y, c4.z, c4.w} };
    uint32_t kk[4]; uint32_t gpack = 0;
    #pragma unroll
    for (int p = 0; p < 4; ++p) {
        float best = u[p][0]; uint32_t g = 0;
        if (u[p][1] > best) { best = u[p][1]; g = 1; }   // strict > = first max
        if (u[p][2] > best) { best = u[p][2]; g = 2; }
        kk[p] = (best > 0.0f) ? (__float_as_uint(best) | 0x80000000u) : 0u;
        gpack |= g << (8 * p);
    }
    key4[t] = make_uint4(kk[0], kk[1], kk[2], kk[3]);
    g4[t] = gpack;
    selx4[t] = 0u;
    int b = (t * 4) / HW;                     // HW % 4 == 0
    #pragma unroll
    for (int p = 0; p < 4; ++p)
        if (kk[p])
            atomicAdd(&hist[(size_t)b * HBINS + ((kk[p] >> 16) & 32767u)],
                      costOf((gpack >> (8 * p)) & 3u));
}

// K2: per-batch block. Coarse sums from fine hist (no atomics), coarse
// shfl-scan -> crossing coarse chunk; fine scan of its 128 bins -> b2/usage/hl.
__global__ __launch_bounds__(256) void k_cut(const uint32_t* __restrict__ hist,
                                             const int* __restrict__ budget_ptr,
                                             uint32_t* __restrict__ res) {
    int b = blockIdx.x;
    int t = threadIdx.x;
    int lane = t & 63, wv = t >> 6;
    uint32_t budget = budgetInt(budget_ptr);
    const uint32_t* hb = hist + (size_t)b * HBINS;

    __shared__ uint32_t csum[256];

    const uint4* h4 = (const uint4*)(hb + (size_t)t * 128);
    uint32_t s = 0;
    #pragma unroll 8
    for (int j = 0; j < 32; ++j) { uint4 v = h4[j]; s += v.x + v.y + v.z + v.w; }
    csum[t] = s;
    __syncthreads();
    if (wv != 0) return;

    int hi = 255 - 4 * lane;
    uint32_t c0 = csum[hi], c1 = csum[hi - 1], c2 = csum[hi - 2], c3 = csum[hi - 3];
    uint32_t cs = c0 + c1 + c2 + c3;
    uint32_t v = cs;
    #pragma unroll
    for (int off = 1; off < 64; off <<= 1) {
        uint32_t o = __shfl_up(v, off);
        if (lane >= off) v += o;
    }
    uint32_t excl = v - cs;
    bool found = (excl <= budget) && (v > budget);
    uint32_t cbin = 0, cusage = 0;
    if (found) {
        uint32_t cum = excl;
        if      (cum + c0 > budget) { cbin = (uint32_t)hi;       cusage = cum; }
        else if ((cum += c0) + c1 > budget) { cbin = (uint32_t)(hi - 1); cusage = cum; }
        else if ((cum += c1) + c2 > budget) { cbin = (uint32_t)(hi - 2); cusage = cum; }
        else                        { cbin = (uint32_t)(hi - 3); cusage = cum + c2; }
    }
    unsigned long long msk = __ballot(found);
    if (msk == 0ull) {                            // no crossing: all valid selected
        if (lane == 0) { res[b] = INV; res[4 + b] = 0u; res[8 + b] = 1u; }
        return;
    }
    int src = __ffsll((long long)msk) - 1;
    cbin   = __shfl(cbin, src);
    cusage = __shfl(cusage, src);

    const uint32_t* fb = hb + (size_t)cbin * 128;
    int fhi = 127 - 2 * lane;
    uint32_t f0 = fb[fhi], f1 = fb[fhi - 1];
    uint32_t fs = f0 + f1;
    v = fs;
    #pragma unroll
    for (int off = 1; off < 64; off <<= 1) {
        uint32_t o = __shfl_up(v, off);
        if (lane >= off) v += o;
    }
    excl = cusage + v - fs;
    found = (excl <= budget) && (excl + fs > budget);
    uint32_t b2 = 0, fusage = 0;
    if (found) {
        if (excl + f0 > budget) { b2 = cbin * 128u + (uint32_t)fhi;       fusage = excl; }
        else                    { b2 = cbin * 128u + (uint32_t)(fhi - 1); fusage = excl + f0; }
    }
    msk = __ballot(found);
    src = __ffsll((long long)msk) - 1;            // nonzero by construction
    b2     = __shfl(b2, src);
    fusage = __shfl(fusage, src);
    if (lane == 0) {
        res[b]     = b2;
        res[4 + b] = fusage;
        uint32_t bs = b2 + 32768u;
        res[8 + b] = (bs >= 65535u) ? INV : ((bs + 1u) << 16);
    }
}

// K3: gather (grid NSL x B_, 256 thr, 4 px/thread) + last-block final.
__global__ __launch_bounds__(256) void k_gf(const uint32_t* __restrict__ key,
                                            const uint8_t* __restrict__ g,
                                            const uint32_t* __restrict__ res,
                                            const int* __restrict__ budget_ptr,
                                            uint32_t* __restrict__ gcnt,
                                            uint64_t* __restrict__ glist,
                                            uint64_t* __restrict__ cand,
                                            uint32_t* __restrict__ done,
                                            uint8_t* __restrict__ selx) {
    int b = blockIdx.y;
    uint32_t b2 = res[b];
    if (b2 == INV) return;                        // uniform: no crossing
    int sl = blockIdx.x;
    int t = threadIdx.x;
    int lane = t & 63, wv = t >> 6;

    __shared__ union {
        struct { uint64_t red5[4]; uint64_t red2[4][4]; } gat;
        struct { uint64_t e[CAP]; uint64_t s[CAP]; uint64_t cd[NCAND]; } fin;
    } sm;
    __shared__ int lastFlag;

    // ---- gather phase ----
    const uint32_t* kb = key + (size_t)b * HW;
    const uint8_t*  gb = g   + (size_t)b * HW;
    uint64_t m5 = 0, a0 = 0, a1 = 0, a2 = 0, a3 = 0;
    for (int p = t; p < SLPX; p += 256) {
        uint32_t pix = (uint32_t)(sl * SLPX + p);
        uint32_t k = kb[pix];
        if (!k) continue;
        uint32_t bin = (k >> 16) & 32767u;
        if (bin == b2) {
            uint32_t gg = gb[pix];
            uint32_t idx = atomicAdd(&gcnt[b], 1u);
            if (idx < CAP)   // asc key: (~k, pix) -> utility desc, pix asc
                glist[(size_t)b * CAP + idx] =
                    ((uint64_t)(~k) << 32) | ((uint64_t)pix << 2) | (uint64_t)gg;
        } else if (bin < b2) {
            uint32_t gg = gb[pix];
            if (gg) {        // cost-10 never fits (r <= 9 after bin walk)
                uint64_t m = ((uint64_t)k << 18) | ((uint64_t)(65535u - pix) << 2)
                           | (uint64_t)gg;
                if (gg == 1u) { if (m > m5) m5 = m; }
                else if (m > a3) {
                    if      (m > a0) { a3 = a2; a2 = a1; a1 = a0; a0 = m; }
                    else if (m > a1) { a3 = a2; a2 = a1; a1 = m; }
                    else if (m > a2) { a3 = a2; a2 = m; }
                    else             { a3 = m; }
                }
            }
        }
    }
    #pragma unroll
    for (int off = 32; off; off >>= 1) {          // wave reduce (max / bitonic top-4)
        uint64_t o5 = __shfl_down(m5, off);
        if (o5 > m5) m5 = o5;
        uint64_t b0 = __shfl_down(a0, off), b1 = __shfl_down(a1, off),
                 b2_ = __shfl_down(a2, off), b3 = __shfl_down(a3, off);
        CE(a0, b3); CE(a1, b2_); CE(a2, b1); CE(a3, b0);
        CE(a0, a2); CE(a1, a3); CE(a0, a1); CE(a2, a3);
    }
    if (lane == 0) {
        sm.gat.red5[wv] = m5;
        sm.gat.red2[wv][0] = a0; sm.gat.red2[wv][1] = a1;
        sm.gat.red2[wv][2] = a2; sm.gat.red2[wv][3] = a3;
    }
    __syncthreads();
    if (t == 0) {
        uint64_t g5 = 0, t0 = 0, t1 = 0, t2 = 0, t3 = 0;
        for (int wq = 0; wq < 4; ++wq) {
            if (sm.gat.red5[wq] > g5) g5 = sm.gat.red5[wq];
            #pragma unroll
            for (int q = 0; q < 4; ++q) {
                uint64_t m = sm.gat.red2[wq][q];
                if (m > t3) {
                    if      (m > t0) { t3 = t2; t2 = t1; t1 = t0; t0 = m; }
                    else if (m > t1) { t3 = t2; t2 = t1; t1 = m; }
                    else if (m > t2) { t3 = t2; t2 = m; }
                    else             { t3 = m; }
                }
            }
        }
        uint64_t* cb_ = cand + ((size_t)b * NSL + (size_t)sl) * 5;
        cb_[0] = g5; cb_[1] = t0; cb_[2] = t1; cb_[3] = t2; cb_[4] = t3;
    }
    __syncthreads();

    // ---- completion: last block of this batch runs the final phase ----
    __threadfence();                              // publish glist/cand/gcnt
    if (t == 0) {
        uint32_t old = atomicAdd(&done[b], 1u);
        lastFlag = (old == NSL - 1);
    }
    __syncthreads();
    if (!lastFlag) return;
    __threadfence();                              // acquire

    uint32_t budget = budgetInt(budget_ptr);
    uint32_t cnt = gcnt[b];
    int n = (int)(cnt < (uint32_t)CAP ? cnt : (uint32_t)CAP);
    for (int i = t; i < n; i += 256) sm.fin.e[i] = glist[(size_t)b * CAP + i];
    for (int i = t; i < NCAND; i += 256) sm.fin.cd[i] = cand[(size_t)b * NCAND + i];
    __syncthreads();
    for (int i = t; i < n; i += 256) {            // rank sort (keys distinct)
        uint64_t ei = sm.fin.e[i];
        int rk = 0;
        for (int j = 0; j < n; ++j) rk += (sm.fin.e[j] < ei);
        sm.fin.s[rk] = ei;
    }
    __syncthreads();
    if (wv == 0) {
        // wave-parallel tail-candidate merge (3 cd entries/lane)
        uint64_t w5 = 0, c0 = 0, c1 = 0, c2 = 0, c3 = 0;
        for (int i = lane; i < NCAND; i += 64) {
            uint64_t m = sm.fin.cd[i];
            if (!m) continue;
            if ((m & 3u) == 1u) { if (m > w5) w5 = m; }
            else if (m > c3) {
                if      (m > c0) { c3 = c2; c2 = c1; c1 = c0; c0 = m; }
                else if (m > c1) { c3 = c2; c2 = c1; c1 = m; }
                else if (m > c2) { c3 = c2; c2 = m; }
                else             { c3 = m; }
            }
        }
        #pragma unroll
        for (int off = 32; off; off >>= 1) {
            uint64_t o5 = __shfl_down(w5, off);
            if (o5 > w5) w5 = o5;
            uint64_t b0 = __shfl_down(c0, off), b1 = __shfl_down(c1, off),
                     b2_ = __shfl_down(c2, off), b3 = __shfl_down(c3, off);
            CE(c0, b3); CE(c1, b2_); CE(c2, b1); CE(c3, b0);
            CE(c0, c2); CE(c1, c3); CE(c0, c1); CE(c2, c3);
        }
        if (lane == 0) {
            // serial greedy within bin b*
            uint32_t usage = res[4 + b];
            uint8_t* sx = selx + (size_t)b * HW;
            for (int i = 0; i < n; ++i) {
                uint64_t ei = sm.fin.s[i];
                uint32_t c = costOf((uint32_t)(ei & 3u));
                if (usage + c <= budget) { usage += c; sx[(ei >> 2) & 0xFFFFu] = 1; }
            }
            // exact <=5-pick tail replay below bin b*
            uint64_t c5[5] = { w5, c0, c1, c2, c3 };
            for (int i = 1; i < 5; ++i) {
                uint64_t x = c5[i]; int j = i;
                while (j > 0 && c5[j - 1] < x) { c5[j] = c5[j - 1]; --j; }
                c5[j] = x;
            }
            uint32_t r = budget - usage;          // provably <= 9
            for (int i = 0; i < 5; ++i) {
                uint64_t m = c5[i];
                if (!m) break;
                uint32_t c = costOf((uint32_t)(m & 3u));
                if (c <= r) {
                    r -= c;
                    uint32_t pix = 65535u - (uint32_t)((m >> 2) & 0xFFFFu);
                    sx[pix] = 1;
                }
            }
        }
    }
}

// K4: masked sparse BEV + sel_idx output (c==0 blocks), float4-vectorized.
__global__ void k_sparse(const float* __restrict__ collab, const uint4* __restrict__ key4,
                         const uint32_t* __restrict__ g4, const uint32_t* __restrict__ selx4,
                         const uint32_t* __restrict__ hl_arr,
                         float* __restrict__ out, float* __restrict__ selOut) {
    int tid = blockIdx.x * blockDim.x + threadIdx.x;   // [0, HW/4)
    int c = blockIdx.y, b = blockIdx.z;
    int cls = (c < C_V) ? 0 : ((c < C_V + C_F) ? 1 : 2);
    uint32_t hl = hl_arr[b];                           // >= 1 always
    size_t p4 = (size_t)b * (HW / 4) + (size_t)tid;
    uint4 kk = key4[p4];
    uint32_t gg = g4[p4];
    uint32_t sx = selx4[p4];
    int sc[4];
    uint32_t kv[4] = { kk.x, kk.y, kk.z, kk.w };
    #pragma unroll
    for (int p = 0; p < 4; ++p) {
        bool se = (kv[p] >= hl) || (((sx >> (8 * p)) & 0xFFu) != 0u);
        sc[p] = se ? (int)((gg >> (8 * p)) & 3u) : -1;
    }
    size_t co = ((size_t)(b * C_ALL + c)) * HW + (size_t)tid * 4;
    float4 v = *(const float4*)(collab + co);
    float4 o;
    o.x = (sc[0] == cls) ? v.x : 0.0f;
    o.y = (sc[1] == cls) ? v.y : 0.0f;
    o.z = (sc[2] == cls) ? v.z : 0.0f;
    o.w = (sc[3] == cls) ? v.w : 0.0f;
    *(float4*)(out + co) = o;
    if (c == 0) {
        float4 sf = make_float4((float)sc[0], (float)sc[1], (float)sc[2], (float)sc[3]);
        ((float4*)selOut)[p4] = sf;
    }
}

extern "C" void kernel_launch(void* const* d_in, const int* in_sizes, int n_in,
                              void* d_out, int out_size, void* d_ws, size_t ws_size,
                              hipStream_t stream) {
    (void)in_sizes; (void)n_in; (void)out_size; (void)ws_size;
    const float* collab = (const float*)d_in[0];
    const float* util   = (const float*)d_in[1];
    const int*   budget = (const int*)d_in[2];

    uint8_t*  ws    = (uint8_t*)d_ws;
    uint32_t* hist  = (uint32_t*)(ws + OFF_HIST);
    uint32_t* gcnt  = (uint32_t*)(ws + OFF_GCNT);
    uint32_t* done  = (uint32_t*)(ws + OFF_DONE);
    uint32_t* key   = (uint32_t*)(ws + OFF_KEY);
    uint8_t*  g     = ws + OFF_G;
    uint8_t*  selx  = ws + OFF_SELX;
    uint32_t* res   = (uint32_t*)(ws + OFF_RES);
    uint64_t* glist = (uint64_t*)(ws + OFF_GLIST);
    uint64_t* cand  = (uint64_t*)(ws + OFF_CAND);

    float* outSparse = (float*)d_out;
    float* outSel    = outSparse + (size_t)B_ * C_ALL * HW;

    k_zero <<<(ZERO_U4 + 255) / 256, 256, 0, stream>>>((uint4*)ws);
    k_prep <<<NPIX / 4 / 256, 256, 0, stream>>>(util, (uint4*)key, (uint32_t*)g,
                                                (uint32_t*)selx, hist);
    k_cut  <<<B_, 256, 0, stream>>>(hist, budget, res);
    dim3 gridGF(NSL, B_);
    k_gf   <<<gridGF, 256, 0, stream>>>(key, g, res, budget, gcnt, glist, cand,
                                        done, selx);
    dim3 gridSP(HW / 4 / 256, C_ALL, B_);
    k_sparse<<<gridSP, 256, 0, stream>>>(collab, (const uint4*)key, (const uint32_t*)g,
                                         (const uint32_t*)selx, res + 8,
                                         outSparse, outSel);
}